// Round 2
// 537.921 us; speedup vs baseline: 1.1742x; 1.1742x over previous
//
#include <hip/hip_runtime.h>
#include <math.h>

// ---------------------------------------------------------------------------
// Fully fused: per 64-row tile, one block does
//   X(bf16,LDS bigbuf) -> H=relu(X@We1+be1) (bigbuf) -> EE=H@We2+be2
//   (global fp32 + bigbuf bf16) -> T1=relu(EE@Wt1+bt1) (LDS fp32) -> head.
// HBM traffic ~372 MB total (pred read + EE write + out); weights from L2.
// M=89700, d=512.  512 threads (8 waves), 128 KiB LDS, 1 block/CU.
// ---------------------------------------------------------------------------

#define ALP 2.2f
#define BEL 0.025f
#define GATE_HI 0.4795454545454546f

typedef __attribute__((ext_vector_type(8))) short bf16x8;
typedef __attribute__((ext_vector_type(4))) float f32x4;

__device__ __forceinline__ unsigned short f2bf(float f) {
    unsigned int u = __float_as_uint(f);
    u = (u + 0x7FFF + ((u >> 16) & 1)) >> 16;   // round-to-nearest-even
    return (unsigned short)u;
}

__device__ __forceinline__ void async_copy16(const unsigned short* g, unsigned short* l) {
    __builtin_amdgcn_global_load_lds(
        (const __attribute__((address_space(1))) unsigned int*)(g),
        (__attribute__((address_space(3))) unsigned int*)(l),
        16, 0, 0);
}

// ---------------- prep: transpose K x N fp32 -> N x K bf16 -----------------
__global__ __launch_bounds__(256) void transpose_cvt(
    const float* __restrict__ W, unsigned short* __restrict__ Wt, int K, int N)
{
    __shared__ float t[32][33];
    const int bk = blockIdx.x * 32, bn = blockIdx.y * 32;
    const int tx = threadIdx.x & 31, ty = threadIdx.x >> 5;   // 32 x 8
#pragma unroll
    for (int i = 0; i < 32; i += 8)
        t[ty + i][tx] = W[(size_t)(bk + ty + i) * N + bn + tx];
    __syncthreads();
#pragma unroll
    for (int i = 0; i < 32; i += 8)
        Wt[(size_t)(bn + ty + i) * K + bk + tx] = f2bf(t[tx][ty + i]);
}

// ------------------------------ megakernel ---------------------------------
// LDS layout (bytes), total 131072 (128 KiB):
//   [0,     65536) : bigb [64][512] bf16, XOR-swizzled (X, then H, then EE)
//   [65536,131072) : Bs weight dbuf 2 x [512][32] bf16, swizzled
//                    (aliased after GEMMs: T1s[64][129] f32 + Ws + sm)
#define SMEM_BS    65536
#define SMEM_TOTAL 131072

__device__ __forceinline__ float gate_fn(float p) {
    if (p <= BEL) return 0.0f;
    if (p >= GATE_HI) return 1.0f;
    return ALP * (p - BEL);
}

__global__ __launch_bounds__(512, 2) void fused_mlp(
    const float* __restrict__ pred,
    const unsigned short* __restrict__ We1t, const float* __restrict__ be1,
    const unsigned short* __restrict__ We2t, const float* __restrict__ be2,
    const unsigned short* __restrict__ Wt1t, const float* __restrict__ bt1,
    const float* __restrict__ Wt2,  const float* __restrict__ bt2,
    float* __restrict__ out, int M)
{
    __shared__ __align__(16) unsigned char smem[SMEM_TOTAL];
    unsigned short* bigb = (unsigned short*)(smem);
    unsigned short* Bs   = (unsigned short*)(smem + SMEM_BS);
    float* T1s = (float*)(smem + SMEM_BS);                   // [64][129] f32
    float* Ws  = (float*)(smem + SMEM_BS + 33024);           // [128][4]  f32
    float* sm  = (float*)(smem + SMEM_BS + 33024 + 2048);    // [4][64]   f32

    const int tid  = threadIdx.x;
    const int lane = tid & 63;
    const int wave = tid >> 6;          // 0..7
    const int fm   = lane & 15;
    const int quad = lane >> 4;         // 0..3
    const int m0   = blockIdx.x * 64;

    float* EE = out + (size_t)12 * M;   // edge_embed output (M x 512) fp32

    const int ecol  = fm;               // C/D layout: col = lane&15
    const int erow4 = quad * 4;         //             row = (lane>>4)*4 + reg
    const int wn    = wave * 64;        // GEMM1/2 column slice per wave

    f32x4 acc[4][4];
#pragma unroll
    for (int i = 0; i < 4; ++i)
#pragma unroll
        for (int j = 0; j < 4; ++j) acc[i][j] = (f32x4){0.f, 0.f, 0.f, 0.f};

    //------------------------------------------------------------------
    // Prologue: issue We1 step-0 stage; reg-stage whole X tile -> bigb
    //------------------------------------------------------------------
#pragma unroll
    for (int i = 0; i < 4; ++i) {
        int c = i * 512 + tid;
        int r = c >> 2, q = c & 3;
        int qs = q ^ ((r >> 1) & 3);                 // pre-swizzled source
        async_copy16(We1t + (size_t)r * 512 + qs * 8, Bs + c * 8);
    }
    {   // X: 64 rows x 512 bf16 = 64 KB; thread t: row t>>3, units (t&7)+8j
        const int xr = tid >> 3;
        int grow = m0 + xr; if (grow >= M) grow = M - 1;
        const float* src = pred + (size_t)grow * 512;
        unsigned char* drow = (unsigned char*)bigb + xr * 1024;
        const int swz = (xr & 7) << 4;
#pragma unroll
        for (int j = 0; j < 8; ++j) {
            const int u = (tid & 7) + 8 * j;         // 16B-unit index (8 bf16)
            float4 a = *(const float4*)(src + u * 8);
            float4 b = *(const float4*)(src + u * 8 + 4);
            bf16x8 v;
            v[0] = (short)f2bf(a.x); v[1] = (short)f2bf(a.y);
            v[2] = (short)f2bf(a.z); v[3] = (short)f2bf(a.w);
            v[4] = (short)f2bf(b.x); v[5] = (short)f2bf(b.y);
            v[6] = (short)f2bf(b.z); v[7] = (short)f2bf(b.w);
            *(bf16x8*)(drow + ((u * 16) ^ swz)) = v;
        }
    }
    __syncthreads();

    //------------------------------------------------------------------
    // Phase A: H = relu(X @ We1^T + be1)        (64 x 512)
    //------------------------------------------------------------------
    for (int ks = 0; ks < 16; ++ks) {
        const int cur = ks & 1, nxt = cur ^ 1;
        if (ks < 15) {
#pragma unroll
            for (int i = 0; i < 4; ++i) {
                int c = i * 512 + tid;
                int r = c >> 2, q = c & 3;
                int qs = q ^ ((r >> 1) & 3);
                async_copy16(We1t + (size_t)r * 512 + (ks + 1) * 32 + qs * 8,
                             Bs + nxt * 16384 + c * 8);
            }
        }
        bf16x8 af[4], bfr[4];
        const unsigned char* bb = (const unsigned char*)Bs + cur * 32768;
#pragma unroll
        for (int i = 0; i < 4; ++i) {
            int r = i * 16 + fm;
            af[i] = *(const bf16x8*)((const unsigned char*)bigb + r * 1024 +
                                     ((ks * 64 + quad * 16) ^ ((r & 7) << 4)));
        }
#pragma unroll
        for (int j = 0; j < 4; ++j) {
            int r = wn + j * 16 + fm;
            bfr[j] = *(const bf16x8*)(bb + r * 64 + ((quad * 16) ^ (((r >> 1) & 3) << 4)));
        }
#pragma unroll
        for (int i = 0; i < 4; ++i)
#pragma unroll
            for (int j = 0; j < 4; ++j)
                acc[i][j] = __builtin_amdgcn_mfma_f32_16x16x32_bf16(
                    af[i], bfr[j], acc[i][j], 0, 0, 0);
        __syncthreads();
    }

    // epilogue A: H -> bigb (bf16, swizzled); stage We2 step 0
    {
#pragma unroll
        for (int i = 0; i < 4; ++i) {
            int c = i * 512 + tid;
            int r = c >> 2, q = c & 3;
            int qs = q ^ ((r >> 1) & 3);
            async_copy16(We2t + (size_t)r * 512 + qs * 8, Bs + c * 8);
        }
#pragma unroll
        for (int j = 0; j < 4; ++j) {
            const int col = wn + j * 16 + ecol;
            const float bv = be1[col];
#pragma unroll
            for (int i = 0; i < 4; ++i)
#pragma unroll
                for (int rr = 0; rr < 4; ++rr) {
                    int row = i * 16 + erow4 + rr;
                    float v = fmaxf(acc[i][j][rr] + bv, 0.f);
                    *(unsigned short*)((unsigned char*)bigb + row * 1024 +
                                       ((col * 2) ^ ((row & 7) << 4))) = f2bf(v);
                }
        }
    }
    __syncthreads();

    //------------------------------------------------------------------
    // Phase B: EE = H @ We2^T + be2             (64 x 512)
    //------------------------------------------------------------------
#pragma unroll
    for (int i = 0; i < 4; ++i)
#pragma unroll
        for (int j = 0; j < 4; ++j) acc[i][j] = (f32x4){0.f, 0.f, 0.f, 0.f};

    for (int ks = 0; ks < 16; ++ks) {
        const int cur = ks & 1, nxt = cur ^ 1;
        if (ks < 15) {
#pragma unroll
            for (int i = 0; i < 4; ++i) {
                int c = i * 512 + tid;
                int r = c >> 2, q = c & 3;
                int qs = q ^ ((r >> 1) & 3);
                async_copy16(We2t + (size_t)r * 512 + (ks + 1) * 32 + qs * 8,
                             Bs + nxt * 16384 + c * 8);
            }
        }
        bf16x8 af[4], bfr[4];
        const unsigned char* bb = (const unsigned char*)Bs + cur * 32768;
#pragma unroll
        for (int i = 0; i < 4; ++i) {
            int r = i * 16 + fm;
            af[i] = *(const bf16x8*)((const unsigned char*)bigb + r * 1024 +
                                     ((ks * 64 + quad * 16) ^ ((r & 7) << 4)));
        }
#pragma unroll
        for (int j = 0; j < 4; ++j) {
            int r = wn + j * 16 + fm;
            bfr[j] = *(const bf16x8*)(bb + r * 64 + ((quad * 16) ^ (((r >> 1) & 3) << 4)));
        }
#pragma unroll
        for (int i = 0; i < 4; ++i)
#pragma unroll
            for (int j = 0; j < 4; ++j)
                acc[i][j] = __builtin_amdgcn_mfma_f32_16x16x32_bf16(
                    af[i], bfr[j], acc[i][j], 0, 0, 0);
        __syncthreads();
    }

    // epilogue B: EE fp32 -> global, bf16 -> bigb; stage Wt1 step 0
    {
        {   // GEMM3 B-stage step 0 (512 chunks, 1/thread) into Bs buffer 0
            int c = tid;
            int r = c >> 2, q = c & 3;
            int qs = q ^ ((r >> 1) & 3);
            async_copy16(Wt1t + (size_t)r * 512 + qs * 8, Bs + c * 8);
        }
#pragma unroll
        for (int j = 0; j < 4; ++j) {
            const int col = wn + j * 16 + ecol;
            const float bv = be2[col];
#pragma unroll
            for (int i = 0; i < 4; ++i)
#pragma unroll
                for (int rr = 0; rr < 4; ++rr) {
                    int row = i * 16 + erow4 + rr;
                    float v = acc[i][j][rr] + bv;
                    if (m0 + row < M)
                        EE[(size_t)(m0 + row) * 512 + col] = v;
                    *(unsigned short*)((unsigned char*)bigb + row * 1024 +
                                       ((col * 2) ^ ((row & 7) << 4))) = f2bf(v);
                }
        }
    }
    __syncthreads();

    //------------------------------------------------------------------
    // Phase C: T1 = relu(EE @ Wt1^T + bt1)      (64 x 128)
    //------------------------------------------------------------------
    f32x4 acc3[4];
#pragma unroll
    for (int i = 0; i < 4; ++i) acc3[i] = (f32x4){0.f, 0.f, 0.f, 0.f};
    const int wn3 = wave * 16;          // 8 waves x 16 cols = 128

    for (int ks = 0; ks < 16; ++ks) {
        const int cur = ks & 1, nxt = cur ^ 1;
        if (ks < 15) {
            int c = tid;
            int r = c >> 2, q = c & 3;
            int qs = q ^ ((r >> 1) & 3);
            async_copy16(Wt1t + (size_t)r * 512 + (ks + 1) * 32 + qs * 8,
                         Bs + nxt * 4096 + c * 8);
        }
        bf16x8 af[4], bfr3;
        const unsigned char* bb = (const unsigned char*)Bs + cur * 8192;
#pragma unroll
        for (int i = 0; i < 4; ++i) {
            int r = i * 16 + fm;
            af[i] = *(const bf16x8*)((const unsigned char*)bigb + r * 1024 +
                                     ((ks * 64 + quad * 16) ^ ((r & 7) << 4)));
        }
        {
            int r = wn3 + fm;
            bfr3 = *(const bf16x8*)(bb + r * 64 + ((quad * 16) ^ (((r >> 1) & 3) << 4)));
        }
#pragma unroll
        for (int i = 0; i < 4; ++i)
            acc3[i] = __builtin_amdgcn_mfma_f32_16x16x32_bf16(af[i], bfr3, acc3[i], 0, 0, 0);
        __syncthreads();
    }

    // epilogue C: T1 -> T1s fp32 [64][129] (aliases Bs); load Wt2 -> Ws
    if (tid < 128) {
        float4 w = *(const float4*)&Wt2[tid * 4];
        *(float4*)&Ws[tid * 4] = w;
    }
    {
        const int col = wn3 + ecol;
        const float bv = bt1[col];
#pragma unroll
        for (int i = 0; i < 4; ++i)
#pragma unroll
            for (int rr = 0; rr < 4; ++rr) {
                int row = i * 16 + erow4 + rr;
                T1s[row * 129 + col] = fmaxf(acc3[i][rr] + bv, 0.f);
            }
    }
    __syncthreads();

    //------------------------------------------------------------------
    // Phase D: head — T = T1 @ Wt2 + bt2, softmax, gate, outputs
    //------------------------------------------------------------------
    if (tid < 256) {
        const int row = tid & 63, col = tid >> 6;
        float d = bt2[col];
#pragma unroll
        for (int k = 0; k < 128; ++k)
            d = fmaf(T1s[row * 129 + k], Ws[k * 4 + col], d);
        sm[col * 64 + row] = d;
    }
    __syncthreads();

    if (tid < 64) {
        int r = m0 + tid;
        if (r < M) {
            float v0 = sm[0 * 64 + tid], v1 = sm[1 * 64 + tid];
            float v2 = sm[2 * 64 + tid], v3 = sm[3 * 64 + tid];
            float mx = fmaxf(fmaxf(v0, v1), fmaxf(v2, v3));
            float e0 = expf(v0 - mx), e1 = expf(v1 - mx);
            float e2 = expf(v2 - mx), e3 = expf(v3 - mx);
            float inv = 1.0f / (e0 + e1 + e2 + e3);
            float p0 = e0 * inv, p1 = e1 * inv, p2 = e2 * inv, p3 = e3 * inv;
            float tw0 = 1.0f - p0;

            float* TW = out;
            float* MW = out + (size_t)4 * M;
            float* TO = out + (size_t)8 * M;
            TW[0 * (size_t)M + r] = tw0;
            TW[1 * (size_t)M + r] = p1;
            TW[2 * (size_t)M + r] = p2;
            TW[3 * (size_t)M + r] = p3;
            MW[0 * (size_t)M + r] = gate_fn(tw0);
            MW[1 * (size_t)M + r] = gate_fn(p1);
            MW[2 * (size_t)M + r] = gate_fn(p2);
            MW[3 * (size_t)M + r] = gate_fn(p3);
            *(float4*)&TO[(size_t)r * 4] = make_float4(p0, p1, p2, p3);
        }
    }
}

// ---------------------------------------------------------------------------
extern "C" void kernel_launch(void* const* d_in, const int* in_sizes, int n_in,
                              void* d_out, int out_size, void* d_ws, size_t ws_size,
                              hipStream_t stream)
{
    const float* pred = (const float*)d_in[1];
    const float* We1  = (const float*)d_in[2];
    const float* be1  = (const float*)d_in[3];
    const float* We2  = (const float*)d_in[4];
    const float* be2  = (const float*)d_in[5];
    const float* Wt1  = (const float*)d_in[6];
    const float* bt1  = (const float*)d_in[7];
    const float* Wt2  = (const float*)d_in[8];
    const float* bt2  = (const float*)d_in[9];

    const int M = in_sizes[1] / 512;
    float* out = (float*)d_out;

    // workspace: transposed bf16 weights only (~1.2 MB)
    unsigned short* We1t = (unsigned short*)d_ws;
    unsigned short* We2t = We1t + 512 * 512;
    unsigned short* Wt1t = We2t + 512 * 512;

    dim3 blk(256);
    transpose_cvt<<<dim3(16, 16), blk, 0, stream>>>(We1, We1t, 512, 512);
    transpose_cvt<<<dim3(16, 16), blk, 0, stream>>>(We2, We2t, 512, 512);
    transpose_cvt<<<dim3(16, 4),  blk, 0, stream>>>(Wt1, Wt1t, 512, 128);

    const int mt = (M + 63) / 64;
    fused_mlp<<<dim3(mt), dim3(512), 0, stream>>>(
        pred, We1t, be1, We2t, be2, Wt1t, bt1, Wt2, bt2, out, M);
}

// Round 3
// 499.626 us; speedup vs baseline: 1.2642x; 1.0766x over previous
//
#include <hip/hip_runtime.h>
#include <math.h>

// ---------------------------------------------------------------------------
// Fully fused per 64-row tile:
//   X(bf16,LDS) -> H=relu(X@We1+be1) -> EE=H@We2+be2 (fp32 global + bf16 LDS)
//   -> T1=relu(EE@Wt1+bt1) -> head (softmax/gate) -> out.
// Round 3: ring-3 weight buffers + counted vmcnt (T4), proven st_16x32-style
// swizzle (chunk-bit1 ^= row-bit3), phase-C BK=64 + 2x4 wave grid, setprio.
// LDS = 64 KB bigb + 96 KB ring = 160 KiB (1 block/CU, 8 waves).
// ---------------------------------------------------------------------------

#define ALP 2.2f
#define BEL 0.025f
#define GATE_HI 0.4795454545454546f

typedef __attribute__((ext_vector_type(8))) short bf16x8;
typedef __attribute__((ext_vector_type(4))) float f32x4;

__device__ __forceinline__ unsigned short f2bf(float f) {
    unsigned int u = __float_as_uint(f);
    u = (u + 0x7FFF + ((u >> 16) & 1)) >> 16;   // round-to-nearest-even
    return (unsigned short)u;
}

__device__ __forceinline__ void async_copy16(const unsigned short* g, unsigned short* l) {
    __builtin_amdgcn_global_load_lds(
        (const __attribute__((address_space(1))) unsigned int*)(g),
        (__attribute__((address_space(3))) unsigned int*)(l),
        16, 0, 0);
}

// ---------------- prep: transpose K x N fp32 -> N x K bf16 (3 mats) --------
__global__ __launch_bounds__(256) void transpose_cvt_all(
    const float* __restrict__ W0, const float* __restrict__ W1,
    const float* __restrict__ W2,
    unsigned short* __restrict__ T0, unsigned short* __restrict__ T1,
    unsigned short* __restrict__ T2)
{
    const int z = blockIdx.z;
    const float* W = (z == 0) ? W0 : (z == 1) ? W1 : W2;
    unsigned short* T = (z == 0) ? T0 : (z == 1) ? T1 : T2;
    const int N = (z == 2) ? 128 : 512;       // W is 512 x N
    const int bn = blockIdx.y * 32;
    if (bn >= N) return;
    __shared__ float t[32][33];
    const int bk = blockIdx.x * 32;
    const int tx = threadIdx.x & 31, ty = threadIdx.x >> 5;   // 32 x 8
#pragma unroll
    for (int i = 0; i < 32; i += 8)
        t[ty + i][tx] = W[(size_t)(bk + ty + i) * N + bn + tx];
    __syncthreads();
#pragma unroll
    for (int i = 0; i < 32; i += 8)
        T[(size_t)(bn + ty + i) * 512 + bk + tx] = f2bf(t[tx][ty + i]);
}

// ------------------------------ megakernel ---------------------------------
// LDS (bytes), total 163840:
//   [0,      65536) : bigb [64][512] bf16, swizzled (X -> H -> EE)
//   [65536, 163840) : ring of 3 weight bufs (A/B: 32 KB each; C: 16 KB each)
//                     aliased after GEMMs: T1s[64][129] f32 + Ws + sm
#define SMEM_BS    65536
#define SMEM_TOTAL 163840

__device__ __forceinline__ float gate_fn(float p) {
    if (p <= BEL) return 0.0f;
    if (p >= GATE_HI) return 1.0f;
    return ALP * (p - BEL);
}

// stage 512x32 bf16 weight slice (32 KB) -> ring buf; st_16x32-style
// pre-swizzled source: in-row 16B-chunk q ^= ((r>>3)&1)<<1
__device__ __forceinline__ void stage_w32(const unsigned short* Wt, int k0,
                                          unsigned char* smem, int bufbase, int tid)
{
#pragma unroll
    for (int i = 0; i < 4; ++i) {
        int c = i * 512 + tid;                  // 2048 chunks of 16 B
        int r = c >> 2, q = c & 3;
        int qs = q ^ (((r >> 3) & 1) << 1);
        async_copy16(Wt + (size_t)r * 512 + k0 + qs * 8,
                     (unsigned short*)(smem + bufbase) + (size_t)c * 8);
    }
}

// stage 128x64 bf16 Wt1 slice (16 KB) -> ring buf
__device__ __forceinline__ void stage_c64(const unsigned short* Wt, int k0,
                                          unsigned char* smem, int bufbase, int tid)
{
#pragma unroll
    for (int i = 0; i < 2; ++i) {
        int c = i * 512 + tid;                  // 1024 chunks of 16 B
        int r = c >> 3, q = c & 7;
        int qs = q ^ (((r >> 3) & 1) << 1);
        async_copy16(Wt + (size_t)r * 512 + k0 + qs * 8,
                     (unsigned short*)(smem + bufbase) + (size_t)c * 8);
    }
}

__global__ __launch_bounds__(512, 2) void fused_mlp(
    const float* __restrict__ pred,
    const unsigned short* __restrict__ We1t, const float* __restrict__ be1,
    const unsigned short* __restrict__ We2t, const float* __restrict__ be2,
    const unsigned short* __restrict__ Wt1t, const float* __restrict__ bt1,
    const float* __restrict__ Wt2,  const float* __restrict__ bt2,
    float* __restrict__ out, int M)
{
    __shared__ __align__(16) unsigned char smem[SMEM_TOTAL];
    float* T1s = (float*)(smem + SMEM_BS);                   // [64][129] f32
    float* Ws  = (float*)(smem + SMEM_BS + 33024);           // [128][4]  f32
    float* sm  = (float*)(smem + SMEM_BS + 35072);           // [4][64]   f32

    const int tid  = threadIdx.x;
    const int lane = tid & 63;
    const int wave = tid >> 6;          // 0..7
    const int fm   = lane & 15;
    const int quad = lane >> 4;         // 0..3
    const int m0   = blockIdx.x * 64;

    float* EE = out + (size_t)12 * M;   // edge_embed output (M x 512) fp32

    const int sw   = ((fm >> 3) & 1) << 1;      // chunk-bit1 swizzle selector
    const int qx16 = (quad ^ sw) << 4;          // swizzled chunk byte offset
    const int ecol  = fm;               // C/D: col = lane&15
    const int erow4 = quad * 4;         //      row = (lane>>4)*4 + reg
    const int wn    = wave * 64;        // A/B column slice per wave

    f32x4 acc[4][4];
#pragma unroll
    for (int i = 0; i < 4; ++i)
#pragma unroll
        for (int j = 0; j < 4; ++j) acc[i][j] = (f32x4){0.f, 0.f, 0.f, 0.f};

    //------------------------------------------------------------------
    // Prologue: issue We1 slices 0,1; reg-stage whole X tile -> bigb
    //------------------------------------------------------------------
    stage_w32(We1t, 0,  smem, SMEM_BS,         tid);
    stage_w32(We1t, 32, smem, SMEM_BS + 32768, tid);
    {   // X: 64 rows x 512 bf16; thread t: row t>>3, chunks (t&7)+8j
        const int xr = tid >> 3;
        int grow = m0 + xr; if (grow >= M) grow = M - 1;
        const float* src = pred + (size_t)grow * 512;
        unsigned char* drow = smem + xr * 1024;
        const int xsw = ((xr >> 3) & 1) << 1;
#pragma unroll
        for (int j = 0; j < 8; ++j) {
            const int u = (tid & 7) + 8 * j;    // 16B-chunk (8 bf16)
            float4 a = *(const float4*)(src + u * 8);
            float4 b = *(const float4*)(src + u * 8 + 4);
            bf16x8 v;
            v[0] = (short)f2bf(a.x); v[1] = (short)f2bf(a.y);
            v[2] = (short)f2bf(a.z); v[3] = (short)f2bf(a.w);
            v[4] = (short)f2bf(b.x); v[5] = (short)f2bf(b.y);
            v[6] = (short)f2bf(b.z); v[7] = (short)f2bf(b.w);
            *(bf16x8*)(drow + ((u ^ xsw) << 4)) = v;
        }
    }
    __syncthreads();

    //------------------------------------------------------------------
    // Phase A: H = relu(X @ We1^T + be1)        (64 x 512), ring-3 BK=32
    //------------------------------------------------------------------
#pragma unroll
    for (int ks = 0; ks < 16; ++ks) {
        if (ks < 14)
            stage_w32(We1t, (ks + 2) * 32, smem,
                      SMEM_BS + ((ks + 2) % 3) * 32768, tid);
        const unsigned char* bb = smem + SMEM_BS + (ks % 3) * 32768;
        bf16x8 af[4], bfr[4];
#pragma unroll
        for (int i = 0; i < 4; ++i) {
            int r = i * 16 + fm;
            af[i] = *(const bf16x8*)(smem + r * 1024 + ks * 64 + qx16);
        }
#pragma unroll
        for (int j = 0; j < 4; ++j) {
            int r = wn + j * 16 + fm;
            bfr[j] = *(const bf16x8*)(bb + r * 64 + qx16);
        }
        __builtin_amdgcn_s_setprio(1);
#pragma unroll
        for (int i = 0; i < 4; ++i)
#pragma unroll
            for (int j = 0; j < 4; ++j)
                acc[i][j] = __builtin_amdgcn_mfma_f32_16x16x32_bf16(
                    af[i], bfr[j], acc[i][j], 0, 0, 0);
        __builtin_amdgcn_s_setprio(0);
        if (ks < 14) { asm volatile("s_waitcnt vmcnt(4)\n\ts_barrier" ::: "memory"); }
        else         { asm volatile("s_waitcnt vmcnt(0)\n\ts_barrier" ::: "memory"); }
    }

    // epilogue A: stage We2 slices 0,1; H -> bigb (bf16, swizzled)
    stage_w32(We2t, 0,  smem, SMEM_BS,         tid);
    stage_w32(We2t, 32, smem, SMEM_BS + 32768, tid);
#pragma unroll
    for (int j = 0; j < 4; ++j) {
        const int col = wn + j * 16 + ecol;
        const float bv = be1[col];
#pragma unroll
        for (int i = 0; i < 4; ++i)
#pragma unroll
            for (int rr = 0; rr < 4; ++rr) {
                int row = i * 16 + erow4 + rr;
                float v = fmaxf(acc[i][j][rr] + bv, 0.f);
                *(unsigned short*)(smem + row * 1024 +
                                   ((col * 2) ^ ((((row) >> 3) & 1) << 5))) = f2bf(v);
            }
    }
    __syncthreads();

    //------------------------------------------------------------------
    // Phase B: EE = H @ We2^T + be2             (64 x 512), ring-3 BK=32
    //------------------------------------------------------------------
#pragma unroll
    for (int i = 0; i < 4; ++i)
#pragma unroll
        for (int j = 0; j < 4; ++j) acc[i][j] = (f32x4){0.f, 0.f, 0.f, 0.f};

#pragma unroll
    for (int ks = 0; ks < 16; ++ks) {
        if (ks < 14)
            stage_w32(We2t, (ks + 2) * 32, smem,
                      SMEM_BS + ((ks + 2) % 3) * 32768, tid);
        const unsigned char* bb = smem + SMEM_BS + (ks % 3) * 32768;
        bf16x8 af[4], bfr[4];
#pragma unroll
        for (int i = 0; i < 4; ++i) {
            int r = i * 16 + fm;
            af[i] = *(const bf16x8*)(smem + r * 1024 + ks * 64 + qx16);
        }
#pragma unroll
        for (int j = 0; j < 4; ++j) {
            int r = wn + j * 16 + fm;
            bfr[j] = *(const bf16x8*)(bb + r * 64 + qx16);
        }
        __builtin_amdgcn_s_setprio(1);
#pragma unroll
        for (int i = 0; i < 4; ++i)
#pragma unroll
            for (int j = 0; j < 4; ++j)
                acc[i][j] = __builtin_amdgcn_mfma_f32_16x16x32_bf16(
                    af[i], bfr[j], acc[i][j], 0, 0, 0);
        __builtin_amdgcn_s_setprio(0);
        if (ks < 14) { asm volatile("s_waitcnt vmcnt(4)\n\ts_barrier" ::: "memory"); }
        else         { asm volatile("s_waitcnt vmcnt(0)\n\ts_barrier" ::: "memory"); }
    }

    // epilogue B: stage Wt1 slices 0,1; EE fp32 -> global + bf16 -> bigb
    stage_c64(Wt1t, 0,  smem, SMEM_BS,         tid);
    stage_c64(Wt1t, 64, smem, SMEM_BS + 16384, tid);
#pragma unroll
    for (int j = 0; j < 4; ++j) {
        const int col = wn + j * 16 + ecol;
        const float bv = be2[col];
#pragma unroll
        for (int i = 0; i < 4; ++i)
#pragma unroll
            for (int rr = 0; rr < 4; ++rr) {
                int row = i * 16 + erow4 + rr;
                float v = acc[i][j][rr] + bv;
                if (m0 + row < M)
                    EE[(size_t)(m0 + row) * 512 + col] = v;
                *(unsigned short*)(smem + row * 1024 +
                                   ((col * 2) ^ ((((row) >> 3) & 1) << 5))) = f2bf(v);
            }
    }
    __syncthreads();

    //------------------------------------------------------------------
    // Phase C: T1 = relu(EE @ Wt1^T + bt1)  (64 x 128), ring-3 BK=64, 2x4 waves
    //------------------------------------------------------------------
    const int wr3 = wave >> 2;          // 0..1 (row group of 32)
    const int wc3 = wave & 3;           // 0..3 (col group of 32)
    f32x4 acc3[2][2];
#pragma unroll
    for (int i = 0; i < 2; ++i)
#pragma unroll
        for (int j = 0; j < 2; ++j) acc3[i][j] = (f32x4){0.f, 0.f, 0.f, 0.f};

#pragma unroll
    for (int ks = 0; ks < 8; ++ks) {
        if (ks < 6)
            stage_c64(Wt1t, (ks + 2) * 64, smem,
                      SMEM_BS + ((ks + 2) % 3) * 16384, tid);
        const unsigned char* bb = smem + SMEM_BS + (ks % 3) * 16384;
#pragma unroll
        for (int kk = 0; kk < 2; ++kk) {
            bf16x8 a2[2], b2[2];
#pragma unroll
            for (int i = 0; i < 2; ++i) {
                int r = wr3 * 32 + i * 16 + fm;
                a2[i] = *(const bf16x8*)(smem + r * 1024 + (ks * 2 + kk) * 64 + qx16);
            }
#pragma unroll
            for (int j = 0; j < 2; ++j) {
                int r = wc3 * 32 + j * 16 + fm;
                b2[j] = *(const bf16x8*)(bb + r * 128 + kk * 64 + qx16);
            }
            __builtin_amdgcn_s_setprio(1);
#pragma unroll
            for (int i = 0; i < 2; ++i)
#pragma unroll
                for (int j = 0; j < 2; ++j)
                    acc3[i][j] = __builtin_amdgcn_mfma_f32_16x16x32_bf16(
                        a2[i], b2[j], acc3[i][j], 0, 0, 0);
            __builtin_amdgcn_s_setprio(0);
        }
        if (ks < 6) { asm volatile("s_waitcnt vmcnt(2)\n\ts_barrier" ::: "memory"); }
        else        { asm volatile("s_waitcnt vmcnt(0)\n\ts_barrier" ::: "memory"); }
    }

    // epilogue C: T1 -> T1s fp32 [64][129]; Wt2 -> Ws
    if (tid < 128) {
        float4 w = *(const float4*)&Wt2[tid * 4];
        *(float4*)&Ws[tid * 4] = w;
    }
#pragma unroll
    for (int j = 0; j < 2; ++j) {
        const int col = wc3 * 32 + j * 16 + ecol;
        const float bv = bt1[col];
#pragma unroll
        for (int i = 0; i < 2; ++i)
#pragma unroll
            for (int rr = 0; rr < 4; ++rr) {
                int row = wr3 * 32 + i * 16 + erow4 + rr;
                T1s[row * 129 + col] = fmaxf(acc3[i][j][rr] + bv, 0.f);
            }
    }
    __syncthreads();

    //------------------------------------------------------------------
    // Phase D: head — T = T1 @ Wt2 + bt2, softmax, gate, outputs
    //------------------------------------------------------------------
    if (tid < 256) {
        const int row = tid & 63, col = tid >> 6;
        float d = bt2[col];
#pragma unroll
        for (int k = 0; k < 128; ++k)
            d = fmaf(T1s[row * 129 + k], Ws[k * 4 + col], d);
        sm[col * 64 + row] = d;
    }
    __syncthreads();

    if (tid < 64) {
        int r = m0 + tid;
        if (r < M) {
            float v0 = sm[0 * 64 + tid], v1 = sm[1 * 64 + tid];
            float v2 = sm[2 * 64 + tid], v3 = sm[3 * 64 + tid];
            float mx = fmaxf(fmaxf(v0, v1), fmaxf(v2, v3));
            float e0 = expf(v0 - mx), e1 = expf(v1 - mx);
            float e2 = expf(v2 - mx), e3 = expf(v3 - mx);
            float inv = 1.0f / (e0 + e1 + e2 + e3);
            float p0 = e0 * inv, p1 = e1 * inv, p2 = e2 * inv, p3 = e3 * inv;
            float tw0 = 1.0f - p0;

            float* TW = out;
            float* MW = out + (size_t)4 * M;
            float* TO = out + (size_t)8 * M;
            TW[0 * (size_t)M + r] = tw0;
            TW[1 * (size_t)M + r] = p1;
            TW[2 * (size_t)M + r] = p2;
            TW[3 * (size_t)M + r] = p3;
            MW[0 * (size_t)M + r] = gate_fn(tw0);
            MW[1 * (size_t)M + r] = gate_fn(p1);
            MW[2 * (size_t)M + r] = gate_fn(p2);
            MW[3 * (size_t)M + r] = gate_fn(p3);
            *(float4*)&TO[(size_t)r * 4] = make_float4(p0, p1, p2, p3);
        }
    }
}

// ---------------------------------------------------------------------------
extern "C" void kernel_launch(void* const* d_in, const int* in_sizes, int n_in,
                              void* d_out, int out_size, void* d_ws, size_t ws_size,
                              hipStream_t stream)
{
    const float* pred = (const float*)d_in[1];
    const float* We1  = (const float*)d_in[2];
    const float* be1  = (const float*)d_in[3];
    const float* We2  = (const float*)d_in[4];
    const float* be2  = (const float*)d_in[5];
    const float* Wt1  = (const float*)d_in[6];
    const float* bt1  = (const float*)d_in[7];
    const float* Wt2  = (const float*)d_in[8];
    const float* bt2  = (const float*)d_in[9];

    const int M = in_sizes[1] / 512;
    float* out = (float*)d_out;

    // workspace: transposed bf16 weights only (~1.2 MB)
    unsigned short* We1t = (unsigned short*)d_ws;
    unsigned short* We2t = We1t + 512 * 512;
    unsigned short* Wt1t = We2t + 512 * 512;

    transpose_cvt_all<<<dim3(16, 16, 3), dim3(256), 0, stream>>>(
        We1, We2, Wt1, We1t, We2t, Wt1t);

    const int mt = (M + 63) / 64;
    fused_mlp<<<dim3(mt), dim3(512), 0, stream>>>(
        pred, We1t, be1, We2t, be2, Wt1t, bt1, Wt2, bt2, out, M);
}